// Round 6
// baseline (313.853 us; speedup 1.0000x reference)
//
#include <hip/hip_runtime.h>
#include <hip/hip_bf16.h>

// WeightedSigLipLoss: N=8192 rows, C=6 classes, D=512 features.
// loss[n] = sum_m softplus(agree[n,m]*(t*sim[n,m]+b)) * w[n]/sum(w)
// sim   = normalize(features) @ normalize(features)^T  (symmetric, bf16 1-pass)
// agree = 2 * targets @ targets^T - 1  (K=32 hi/lo-packed MFMA, err ~1e-6)
// Round 6: BK=128 (4 stages -> half the barrier drains vs r3's 8);
// epilogue reverted to r3's proven MFMA-agree + 2-transc softplus;
// k_final merged into k_gemm via last-block-done pattern (2 dispatches).

#define NROW 8192
#define DIM  512
#define NCLS 6

#define BM 128
#define BK 128
#define NB (NROW / BM)           // 64 block-rows
#define NTRI (NB * (NB + 1) / 2) // 2080 upper-tri blocks = 8 * 260 (bijective swizzle)
#define NSTG 4                   // 4 K-chunks of 128 (K=512)

typedef short s16x8 __attribute__((ext_vector_type(8)));
typedef float f32x4 __attribute__((ext_vector_type(4)));

static __device__ __forceinline__ ushort f2bf(float x) {
    __hip_bfloat16 h = __float2bfloat16(x);
    union { __hip_bfloat16 h; ushort u; } c; c.h = h; return c.u;
}
static __device__ __forceinline__ float bf2f(ushort u) {
    union { __hip_bfloat16 h; ushort u; } c; c.u = u; return __bfloat162float(c.h);
}

// ---------------- kernel 1: normalize + bf16 + target hi/lo pack + wsum parts ----------------
// fpack[n][512] bf16.  tpA/tpB[n][32] bf16 K=32 agree pack:
//   tpA k: [hi(6) | lo(6) | hi(6) | 0...]   tpB k: [hi(6) | hi(6) | lo(6) | 0...]
// one 16x16x32 MFMA = hi.hi + lo.hi + hi.lo  (exact to ~1e-6).
__global__ __launch_bounds__(256) void k_prep(const float* __restrict__ feat,
                                              const float* __restrict__ tgt,
                                              const float* __restrict__ w,
                                              ushort* __restrict__ fpack,
                                              ushort* __restrict__ tpA,
                                              ushort* __restrict__ tpB,
                                              float* __restrict__ partial,
                                              float* __restrict__ wpart,
                                              unsigned* __restrict__ counter) {
    const int wave = threadIdx.x >> 6, lane = threadIdx.x & 63;
    const int row = blockIdx.x * 4 + wave;
    const float* fr = feat + (size_t)row * DIM;
    float4 v0 = *(const float4*)(fr + lane * 4);
    float4 v1 = *(const float4*)(fr + 256 + lane * 4);
    float ss = v0.x*v0.x + v0.y*v0.y + v0.z*v0.z + v0.w*v0.w
             + v1.x*v1.x + v1.y*v1.y + v1.z*v1.z + v1.w*v1.w;
#pragma unroll
    for (int m = 1; m < 64; m <<= 1) ss += __shfl_xor(ss, m);
    const float inv = 1.f / fmaxf(sqrtf(ss), 1e-12f);

    float vals[8] = {v0.x, v0.y, v0.z, v0.w, v1.x, v1.y, v1.z, v1.w};
    ushort hi[8];
#pragma unroll
    for (int i = 0; i < 8; ++i) hi[i] = f2bf(vals[i] * inv);
    ushort* dst = fpack + (size_t)row * 512;
    *(ushort4*)(dst + lane * 4)       = make_ushort4(hi[0], hi[1], hi[2], hi[3]);
    *(ushort4*)(dst + 256 + lane * 4) = make_ushort4(hi[4], hi[5], hi[6], hi[7]);

    // target K=32 pack: lane == k slot
    if (lane < 32) {
        float ta = 0.f, tb = 0.f;
        if (lane < 18) {
            int c = (lane < 6) ? lane : (lane < 12 ? lane - 6 : lane - 12);
            float x = tgt[(size_t)row * NCLS + c];
            ushort h = f2bf(x);
            float hf = bf2f(h);
            float l = x - hf;
            if (lane < 6)       { ta = hf; tb = hf; }
            else if (lane < 12) { ta = l;  tb = hf; }
            else                { ta = hf; tb = l;  }
        }
        tpA[(size_t)row * 32 + lane] = f2bf(ta);
        tpB[(size_t)row * 32 + lane] = f2bf(tb);
    }

    __shared__ float red[4];
    if (lane == 0) {
        partial[row] = 0.f;
        red[wave] = w[row];
    }
    __syncthreads();
    if (threadIdx.x == 0) {
        wpart[blockIdx.x] = red[0] + red[1] + red[2] + red[3];
        if (blockIdx.x == 0) *counter = 0u;
    }
}

// ---------------- staging via global_load_lds (16B), linear LDS dest [G21] ----------------
// 128 rows x 128 bf16 (src stride 512): 2048 chunks of 16B, 256 threads x 8.
__device__ __forceinline__ void stage_f(const ushort* __restrict__ src,
                                        ushort* lds, int tid) {
#pragma unroll
    for (int i = 0; i < 8; ++i) {
        int q = i * 256 + tid;
        int r = q >> 4, c = q & 15;
        __builtin_amdgcn_global_load_lds(
            (const __attribute__((address_space(1))) void*)(src + (size_t)r * 512 + c * 8),
            (__attribute__((address_space(3))) void*)(lds + q * 8),
            16, 0, 0);
    }
}
// 128 rows x 32 bf16 (src stride 32): 512 chunks of 16B, 256 threads x 2.
__device__ __forceinline__ void stage_t(const ushort* __restrict__ src,
                                        ushort* lds, int tid) {
#pragma unroll
    for (int i = 0; i < 2; ++i) {
        int q = i * 256 + tid;
        int r = q >> 2, c = q & 3;
        __builtin_amdgcn_global_load_lds(
            (const __attribute__((address_space(1))) void*)(src + (size_t)r * 32 + c * 8),
            (__attribute__((address_space(3))) void*)(lds + q * 8),
            16, 0, 0);
    }
}

// ---------------- kernel 2: fused upper-tri GEMM + softplus + final scale ----------------
// Single-buffer, BK=128: stage -> sync -> 64 MFMA (4 kk-slices) -> sync, 4 stages,
// then K=32 agree stage. 128x128 tile, 4 waves (2x2), 4x4 16x16x32 fragments.
// Last block to finish performs the final out[] scale (saves a dispatch).
__global__ __launch_bounds__(256, 2) void k_gemm(
    const ushort* __restrict__ fpack, const ushort* __restrict__ tpA,
    const ushort* __restrict__ tpB, const float* __restrict__ tp,
    const float* __restrict__ bp, const float* __restrict__ w,
    float* __restrict__ partial, float* __restrict__ wpart,
    unsigned* __restrict__ counter, float* __restrict__ out) {

    // bijective XCD swizzle (T1): NTRI = 8*260
    const int orig = blockIdx.x;
    const int b = (orig & 7) * (NTRI / 8) + (orig >> 3);
    // linear index -> upper-tri (bi, bj)
    int bi = 0, rem = b;
    while (rem >= NB - bi) { rem -= NB - bi; ++bi; }
    const int bj = bi + rem;

    __shared__ ushort sA[BM * BK];   // 32 KB
    __shared__ ushort sB[BM * BK];   // 32 KB

    const int tid = threadIdx.x;
    const int lane = tid & 63;
    const int wave = tid >> 6;
    const int wr = wave >> 1, wc = wave & 1;   // 2x2 waves, 64x64 each

    const float tt = *tp, bb = *bp;

    f32x4 accS[4][4], accT[4][4];
#pragma unroll
    for (int i = 0; i < 4; ++i)
#pragma unroll
        for (int j = 0; j < 4; ++j) {
            accS[i][j] = (f32x4){0.f, 0.f, 0.f, 0.f};
            accT[i][j] = (f32x4){0.f, 0.f, 0.f, 0.f};
        }

    const ushort* baseA = fpack + (size_t)(bi * BM) * 512;
    const ushort* baseB = fpack + (size_t)(bj * BM) * 512;

    for (int s = 0; s < NSTG; ++s) {
        stage_f(baseA + s * BK, &sA[0], tid);
        stage_f(baseB + s * BK, &sB[0], tid);
        __syncthreads();
#pragma unroll
        for (int kk = 0; kk < 4; ++kk) {
            s16x8 af[4], bg[4];
            const int kb = kk * 32 + (lane >> 4) * 8;
            const int rr = lane & 15;
#pragma unroll
            for (int i = 0; i < 4; ++i)
                af[i] = *(const s16x8*)(&sA[(wr * 64 + i * 16 + rr) * BK + kb]);
#pragma unroll
            for (int j = 0; j < 4; ++j)
                bg[j] = *(const s16x8*)(&sB[(wc * 64 + j * 16 + rr) * BK + kb]);
#pragma unroll
            for (int i = 0; i < 4; ++i)
#pragma unroll
                for (int j = 0; j < 4; ++j)
                    accS[i][j] = __builtin_amdgcn_mfma_f32_16x16x32_bf16(
                        af[i], bg[j], accS[i][j], 0, 0, 0);
        }
        __syncthreads();
    }

    // ---- agree stage: K=32 target pack ----
    stage_t(tpA + (size_t)(bi * BM) * 32, &sA[0], tid);
    stage_t(tpB + (size_t)(bj * BM) * 32, &sB[0], tid);
    __syncthreads();
    {
        s16x8 af[4], bg[4];
        const int kb = (lane >> 4) * 8;
        const int rr = lane & 15;
#pragma unroll
        for (int i = 0; i < 4; ++i)
            af[i] = *(const s16x8*)(&sA[(wr * 64 + i * 16 + rr) * 32 + kb]);
#pragma unroll
        for (int j = 0; j < 4; ++j)
            bg[j] = *(const s16x8*)(&sB[(wc * 64 + j * 16 + rr) * 32 + kb]);
#pragma unroll
        for (int i = 0; i < 4; ++i)
#pragma unroll
            for (int j = 0; j < 4; ++j)
                accT[i][j] = __builtin_amdgcn_mfma_f32_16x16x32_bf16(
                    af[i], bg[j], accT[i][j], 0, 0, 0);
    }

    // ---- epilogue: agree + softplus + row/col partial sums ----
    // C/D layout (m89): col = lane&15, row = (lane>>4)*4 + r
    float rowsum[4][4];
    float colsum[4];
#pragma unroll
    for (int i = 0; i < 4; ++i)
#pragma unroll
        for (int r = 0; r < 4; ++r) rowsum[i][r] = 0.f;
#pragma unroll
    for (int j = 0; j < 4; ++j) colsum[j] = 0.f;

#pragma unroll
    for (int i = 0; i < 4; ++i)
#pragma unroll
        for (int j = 0; j < 4; ++j)
#pragma unroll
            for (int r = 0; r < 4; ++r) {
                const float agree = fmaf(2.f, accT[i][j][r], -1.f);
                const float e = agree * fmaf(tt, accS[i][j][r], bb);
                // softplus(e), stable: max(e,0) + log(1+exp(-|e|))
                const float sp = fmaxf(e, 0.f) + __logf(1.f + __expf(-fabsf(e)));
                rowsum[i][r] += sp;
                colsum[j] += sp;
            }

    // row sums: reduce across the 16 col-lanes (bits 0..3)
#pragma unroll
    for (int i = 0; i < 4; ++i)
#pragma unroll
        for (int r = 0; r < 4; ++r) {
            float v = rowsum[i][r];
            v += __shfl_xor(v, 1); v += __shfl_xor(v, 2);
            v += __shfl_xor(v, 4); v += __shfl_xor(v, 8);
            if ((lane & 15) == 0)
                atomicAdd(&partial[bi * BM + wr * 64 + i * 16 + (lane >> 4) * 4 + r], v);
        }
    // col sums (transpose contribution), off-diagonal blocks only
    if (bi != bj) {
#pragma unroll
        for (int j = 0; j < 4; ++j) {
            float v = colsum[j];
            v += __shfl_xor(v, 16); v += __shfl_xor(v, 32);
            if (lane < 16)
                atomicAdd(&partial[bj * BM + wc * 64 + j * 16 + lane], v);
        }
    }

    // ---- last-block-done: final scale (merged k_final) ----
    __threadfence();                       // make our atomics visible device-wide
    __shared__ bool sLast;
    if (tid == 0)
        sLast = (atomicAdd(counter, 1u) == NTRI - 1);
    __syncthreads();
    if (sLast) {
        // wsum reduce from per-block parts (written by k_prep, flushed at kernel end)
        __shared__ float red[4];
        float s = 0.f;
        for (int i = tid; i < NROW / 4; i += 256) s += wpart[i];
#pragma unroll
        for (int m = 1; m < 64; m <<= 1) s += __shfl_xor(s, m);
        if ((tid & 63) == 0) red[tid >> 6] = s;
        __syncthreads();
        const float wsum = red[0] + red[1] + red[2] + red[3];
        // read partial via atomic-fetch (coherence point) — other XCDs' adds
        for (int i = tid; i < NROW; i += 256)
            out[i] = atomicAdd(&partial[i], 0.f) * w[i] / wsum;
    }
}

extern "C" void kernel_launch(void* const* d_in, const int* in_sizes, int n_in,
                              void* d_out, int out_size, void* d_ws, size_t ws_size,
                              hipStream_t stream) {
    // inputs: 0=logits(unused), 1=targets, 2=features, 3=weights, 4=t, 5=b
    const float* targets  = (const float*)d_in[1];
    const float* features = (const float*)d_in[2];
    const float* weights  = (const float*)d_in[3];
    const float* tp       = (const float*)d_in[4];
    const float* bp       = (const float*)d_in[5];
    float* out = (float*)d_out;

    // workspace layout (~9.1 MB)
    char* p = (char*)d_ws;
    ushort*   fpack   = (ushort*)p;   p += (size_t)NROW * 512 * sizeof(ushort); // 8 MB
    ushort*   tpA     = (ushort*)p;   p += (size_t)NROW * 32 * sizeof(ushort);  // 0.5 MB
    ushort*   tpB     = (ushort*)p;   p += (size_t)NROW * 32 * sizeof(ushort);  // 0.5 MB
    float*    partial = (float*)p;    p += (size_t)NROW * sizeof(float);        // 32 KB
    float*    wpart   = (float*)p;    p += (size_t)(NROW / 4) * sizeof(float);  // 8 KB
    unsigned* counter = (unsigned*)p;

    k_prep<<<NROW / 4, 256, 0, stream>>>(features, targets, weights, fpack, tpA, tpB,
                                         partial, wpart, counter);
    k_gemm<<<NTRI, 256, 0, stream>>>(fpack, tpA, tpB, tp, bp, weights,
                                     partial, wpart, counter, out);
}

// Round 8
// 276.381 us; speedup vs baseline: 1.1356x; 1.1356x over previous
//
#include <hip/hip_runtime.h>
#include <hip/hip_bf16.h>

// WeightedSigLipLoss: N=8192 rows, C=6 classes, D=512 features.
// loss[n] = sum_m softplus(agree[n,m]*(t*sim[n,m]+b)) * w[n]/sum(w)
// sim   = normalize(features) @ normalize(features)^T  (symmetric, bf16 1-pass)
// agree = 2 * targets @ targets^T - 1  (K=32 hi/lo-packed MFMA, err ~1e-6)
// Round 7 (resubmit; r7 bench was an acquisition timeout): best-of composition.
// r3's proven k_gemm loop VERBATIM (BK=64, 8 single-buffered stages, dual
// accS/accT, 2-transc softplus; 86 us measured; r4 dbuf / r5 dot6-epilogue /
// r6 BK=128 all regressed) + r5/r6 aux wins (wpart instead of global atomic
// wsum, merged last-block final scale) + target pack staged up-front into
// separate LDS (kills the serial tail drain).

#define NROW 8192
#define DIM  512
#define NCLS 6

#define BM 128
#define BK 64
#define NB (NROW / BM)           // 64 block-rows
#define NTRI (NB * (NB + 1) / 2) // 2080 upper-tri blocks = 8 * 260 (bijective swizzle)
#define NSTG 8                   // 8 K-chunks of 64 (K=512)

typedef short s16x8 __attribute__((ext_vector_type(8)));
typedef float f32x4 __attribute__((ext_vector_type(4)));

static __device__ __forceinline__ ushort f2bf(float x) {
    __hip_bfloat16 h = __float2bfloat16(x);
    union { __hip_bfloat16 h; ushort u; } c; c.h = h; return c.u;
}
static __device__ __forceinline__ float bf2f(ushort u) {
    union { __hip_bfloat16 h; ushort u; } c; c.u = u; return __bfloat162float(c.h);
}

// ---------------- kernel 1: normalize + bf16 + target hi/lo pack + wsum parts ----------------
// fpack[n][512] bf16.  tpA/tpB[n][32] bf16 K=32 agree pack:
//   tpA k: [hi(6) | lo(6) | hi(6) | 0...]   tpB k: [hi(6) | hi(6) | lo(6) | 0...]
// one 16x16x32 MFMA = hi.hi + lo.hi + hi.lo  (exact to ~1e-6).
__global__ __launch_bounds__(256) void k_prep(const float* __restrict__ feat,
                                              const float* __restrict__ tgt,
                                              const float* __restrict__ w,
                                              ushort* __restrict__ fpack,
                                              ushort* __restrict__ tpA,
                                              ushort* __restrict__ tpB,
                                              float* __restrict__ partial,
                                              float* __restrict__ wpart,
                                              unsigned* __restrict__ counter) {
    const int wave = threadIdx.x >> 6, lane = threadIdx.x & 63;
    const int row = blockIdx.x * 4 + wave;
    const float* fr = feat + (size_t)row * DIM;
    float4 v0 = *(const float4*)(fr + lane * 4);
    float4 v1 = *(const float4*)(fr + 256 + lane * 4);
    float ss = v0.x*v0.x + v0.y*v0.y + v0.z*v0.z + v0.w*v0.w
             + v1.x*v1.x + v1.y*v1.y + v1.z*v1.z + v1.w*v1.w;
#pragma unroll
    for (int m = 1; m < 64; m <<= 1) ss += __shfl_xor(ss, m);
    const float inv = 1.f / fmaxf(sqrtf(ss), 1e-12f);

    float vals[8] = {v0.x, v0.y, v0.z, v0.w, v1.x, v1.y, v1.z, v1.w};
    ushort hi[8];
#pragma unroll
    for (int i = 0; i < 8; ++i) hi[i] = f2bf(vals[i] * inv);
    ushort* dst = fpack + (size_t)row * 512;
    *(ushort4*)(dst + lane * 4)       = make_ushort4(hi[0], hi[1], hi[2], hi[3]);
    *(ushort4*)(dst + 256 + lane * 4) = make_ushort4(hi[4], hi[5], hi[6], hi[7]);

    // target K=32 pack: lane == k slot
    if (lane < 32) {
        float ta = 0.f, tb = 0.f;
        if (lane < 18) {
            int c = (lane < 6) ? lane : (lane < 12 ? lane - 6 : lane - 12);
            float x = tgt[(size_t)row * NCLS + c];
            ushort h = f2bf(x);
            float hf = bf2f(h);
            float l = x - hf;
            if (lane < 6)       { ta = hf; tb = hf; }
            else if (lane < 12) { ta = l;  tb = hf; }
            else                { ta = hf; tb = l;  }
        }
        tpA[(size_t)row * 32 + lane] = f2bf(ta);
        tpB[(size_t)row * 32 + lane] = f2bf(tb);
    }

    __shared__ float red[4];
    if (lane == 0) {
        partial[row] = 0.f;
        red[wave] = w[row];
    }
    __syncthreads();
    if (threadIdx.x == 0) {
        wpart[blockIdx.x] = red[0] + red[1] + red[2] + red[3];
        if (blockIdx.x == 0) *counter = 0u;
    }
}

// ---------------- staging via global_load_lds (16B), linear LDS dest [G21] ----------------
// 128 rows x 64 bf16 (src stride 512): 1024 chunks of 16B, 256 threads x 4.
__device__ __forceinline__ void stage_f(const ushort* __restrict__ src,
                                        ushort* lds, int tid) {
#pragma unroll
    for (int i = 0; i < 4; ++i) {
        int q = i * 256 + tid;
        int r = q >> 3, c = q & 7;
        __builtin_amdgcn_global_load_lds(
            (const __attribute__((address_space(1))) void*)(src + (size_t)r * 512 + c * 8),
            (__attribute__((address_space(3))) void*)(lds + q * 8),
            16, 0, 0);
    }
}
// 128 rows x 32 bf16 (src stride 32): 512 chunks of 16B, 256 threads x 2.
__device__ __forceinline__ void stage_t(const ushort* __restrict__ src,
                                        ushort* lds, int tid) {
#pragma unroll
    for (int i = 0; i < 2; ++i) {
        int q = i * 256 + tid;
        int r = q >> 2, c = q & 3;
        __builtin_amdgcn_global_load_lds(
            (const __attribute__((address_space(1))) void*)(src + (size_t)r * 32 + c * 8),
            (__attribute__((address_space(3))) void*)(lds + q * 8),
            16, 0, 0);
    }
}

// ---------------- kernel 2: fused upper-tri GEMM + softplus + final scale ----------------
// r3-proven loop: stage -> sync -> 32 MFMA -> sync, 8 stages (BK=64).
// Targets staged once up-front into separate LDS (no tail drain).
// Last block to finish performs the final out[] scale (saves a dispatch).
__global__ __launch_bounds__(256, 3) void k_gemm(
    const ushort* __restrict__ fpack, const ushort* __restrict__ tpA,
    const ushort* __restrict__ tpB, const float* __restrict__ tp,
    const float* __restrict__ bp, const float* __restrict__ w,
    float* __restrict__ partial, float* __restrict__ wpart,
    unsigned* __restrict__ counter, float* __restrict__ out) {

    // bijective XCD swizzle (T1): NTRI = 8*260
    const int orig = blockIdx.x;
    const int b = (orig & 7) * (NTRI / 8) + (orig >> 3);
    // linear index -> upper-tri (bi, bj)
    int bi = 0, rem = b;
    while (rem >= NB - bi) { rem -= NB - bi; ++bi; }
    const int bj = bi + rem;

    __shared__ ushort sA[BM * BK];    // 16 KB
    __shared__ ushort sB[BM * BK];    // 16 KB
    __shared__ ushort sTa[BM * 32];   // 8 KB (target pack A)
    __shared__ ushort sTb[BM * 32];   // 8 KB (target pack B)

    const int tid = threadIdx.x;
    const int lane = tid & 63;
    const int wave = tid >> 6;
    const int wr = wave >> 1, wc = wave & 1;   // 2x2 waves, 64x64 each

    const float tt = *tp, bb = *bp;

    f32x4 accS[4][4], accT[4][4];
#pragma unroll
    for (int i = 0; i < 4; ++i)
#pragma unroll
        for (int j = 0; j < 4; ++j) {
            accS[i][j] = (f32x4){0.f, 0.f, 0.f, 0.f};
            accT[i][j] = (f32x4){0.f, 0.f, 0.f, 0.f};
        }

    const ushort* baseA = fpack + (size_t)(bi * BM) * 512;
    const ushort* baseB = fpack + (size_t)(bj * BM) * 512;

    // stage targets once, alongside the first sim stage; drained by the first barrier
    stage_t(tpA + (size_t)(bi * BM) * 32, &sTa[0], tid);
    stage_t(tpB + (size_t)(bj * BM) * 32, &sTb[0], tid);

    for (int s = 0; s < NSTG; ++s) {
        stage_f(baseA + s * 64, &sA[0], tid);
        stage_f(baseB + s * 64, &sB[0], tid);
        __syncthreads();
#pragma unroll
        for (int kk = 0; kk < 2; ++kk) {
            s16x8 af[4], bg[4];
            const int kb = kk * 32 + (lane >> 4) * 8;
            const int rr = lane & 15;
#pragma unroll
            for (int i = 0; i < 4; ++i)
                af[i] = *(const s16x8*)(&sA[(wr * 64 + i * 16 + rr) * BK + kb]);
#pragma unroll
            for (int j = 0; j < 4; ++j)
                bg[j] = *(const s16x8*)(&sB[(wc * 64 + j * 16 + rr) * BK + kb]);
#pragma unroll
            for (int i = 0; i < 4; ++i)
#pragma unroll
                for (int j = 0; j < 4; ++j)
                    accS[i][j] = __builtin_amdgcn_mfma_f32_16x16x32_bf16(
                        af[i], bg[j], accS[i][j], 0, 0, 0);
        }
        __syncthreads();
    }

    // ---- agree: K=32 target pack, staged up-front in sTa/sTb ----
    {
        s16x8 af[4], bg[4];
        const int kb = (lane >> 4) * 8;
        const int rr = lane & 15;
#pragma unroll
        for (int i = 0; i < 4; ++i)
            af[i] = *(const s16x8*)(&sTa[(wr * 64 + i * 16 + rr) * 32 + kb]);
#pragma unroll
        for (int j = 0; j < 4; ++j)
            bg[j] = *(const s16x8*)(&sTb[(wc * 64 + j * 16 + rr) * 32 + kb]);
#pragma unroll
        for (int i = 0; i < 4; ++i)
#pragma unroll
            for (int j = 0; j < 4; ++j)
                accT[i][j] = __builtin_amdgcn_mfma_f32_16x16x32_bf16(
                    af[i], bg[j], accT[i][j], 0, 0, 0);
    }

    // ---- epilogue: agree + softplus + row/col partial sums ----
    // C/D layout (m89): col = lane&15, row = (lane>>4)*4 + r
    float rowsum[4][4];
    float colsum[4];
#pragma unroll
    for (int i = 0; i < 4; ++i)
#pragma unroll
        for (int r = 0; r < 4; ++r) rowsum[i][r] = 0.f;
#pragma unroll
    for (int j = 0; j < 4; ++j) colsum[j] = 0.f;

#pragma unroll
    for (int i = 0; i < 4; ++i)
#pragma unroll
        for (int j = 0; j < 4; ++j)
#pragma unroll
            for (int r = 0; r < 4; ++r) {
                const float agree = fmaf(2.f, accT[i][j][r], -1.f);
                const float e = agree * fmaf(tt, accS[i][j][r], bb);
                // softplus(e), stable: max(e,0) + log(1+exp(-|e|))
                const float sp = fmaxf(e, 0.f) + __logf(1.f + __expf(-fabsf(e)));
                rowsum[i][r] += sp;
                colsum[j] += sp;
            }

    // row sums: reduce across the 16 col-lanes (bits 0..3)
#pragma unroll
    for (int i = 0; i < 4; ++i)
#pragma unroll
        for (int r = 0; r < 4; ++r) {
            float v = rowsum[i][r];
            v += __shfl_xor(v, 1); v += __shfl_xor(v, 2);
            v += __shfl_xor(v, 4); v += __shfl_xor(v, 8);
            if ((lane & 15) == 0)
                atomicAdd(&partial[bi * BM + wr * 64 + i * 16 + (lane >> 4) * 4 + r], v);
        }
    // col sums (transpose contribution), off-diagonal blocks only
    if (bi != bj) {
#pragma unroll
        for (int j = 0; j < 4; ++j) {
            float v = colsum[j];
            v += __shfl_xor(v, 16); v += __shfl_xor(v, 32);
            if (lane < 16)
                atomicAdd(&partial[bj * BM + wc * 64 + j * 16 + lane], v);
        }
    }

    // ---- last-block-done: final scale (merged k_final, r6-proven) ----
    __threadfence();                       // make our atomics visible device-wide
    __shared__ bool sLast;
    if (tid == 0)
        sLast = (atomicAdd(counter, 1u) == NTRI - 1);
    __syncthreads();
    if (sLast) {
        __shared__ float red[4];
        float s = 0.f;
        for (int i = tid; i < NROW / 4; i += 256) s += wpart[i];
#pragma unroll
        for (int m = 1; m < 64; m <<= 1) s += __shfl_xor(s, m);
        if ((tid & 63) == 0) red[tid >> 6] = s;
        __syncthreads();
        const float wsum = red[0] + red[1] + red[2] + red[3];
        // read partial via atomic-fetch (coherence point for other XCDs' adds)
        for (int i = tid; i < NROW; i += 256)
            out[i] = atomicAdd(&partial[i], 0.f) * w[i] / wsum;
    }
}

extern "C" void kernel_launch(void* const* d_in, const int* in_sizes, int n_in,
                              void* d_out, int out_size, void* d_ws, size_t ws_size,
                              hipStream_t stream) {
    // inputs: 0=logits(unused), 1=targets, 2=features, 3=weights, 4=t, 5=b
    const float* targets  = (const float*)d_in[1];
    const float* features = (const float*)d_in[2];
    const float* weights  = (const float*)d_in[3];
    const float* tp       = (const float*)d_in[4];
    const float* bp       = (const float*)d_in[5];
    float* out = (float*)d_out;

    // workspace layout (~9.1 MB)
    char* p = (char*)d_ws;
    ushort*   fpack   = (ushort*)p;   p += (size_t)NROW * 512 * sizeof(ushort); // 8 MB
    ushort*   tpA     = (ushort*)p;   p += (size_t)NROW * 32 * sizeof(ushort);  // 0.5 MB
    ushort*   tpB     = (ushort*)p;   p += (size_t)NROW * 32 * sizeof(ushort);  // 0.5 MB
    float*    partial = (float*)p;    p += (size_t)NROW * sizeof(float);        // 32 KB
    float*    wpart   = (float*)p;    p += (size_t)(NROW / 4) * sizeof(float);  // 8 KB
    unsigned* counter = (unsigned*)p;

    k_prep<<<NROW / 4, 256, 0, stream>>>(features, targets, weights, fpack, tpA, tpB,
                                         partial, wpart, counter);
    k_gemm<<<NTRI, 256, 0, stream>>>(fpack, tpA, tpB, tp, bp, weights,
                                     partial, wpart, counter, out);
}

// Round 9
// 161.322 us; speedup vs baseline: 1.9455x; 1.7132x over previous
//
#include <hip/hip_runtime.h>
#include <hip/hip_bf16.h>

// WeightedSigLipLoss: N=8192 rows, C=6 classes, D=512 features.
// loss[n] = sum_m softplus(agree[n,m]*(t*sim[n,m]+b)) * w[n]/sum(w)
// sim   = normalize(features) @ normalize(features)^T  (symmetric, bf16 1-pass)
// agree = 2 * targets @ targets^T - 1  (K=32 hi/lo-packed MFMA, err ~1e-6)
// Round 9: restoration of the two proven-best pieces, nothing else.
//  - k_gemm: r3 VERBATIM (86 us measured). Deviations all regressed:
//    r4 dbuf, r5 dot6-epilogue, r6 BK=128, r8 threadfence-merged-final
//    (threadfence's L2 writeback evicted co-resident blocks' panels: 210 us).
//  - aux: r5's structure (wpart in k_prep, separate k_final, no memset).

#define NROW 8192
#define DIM  512
#define NCLS 6

#define BM 128
#define BK 64
#define NB (NROW / BM)           // 64 block-rows
#define NTRI (NB * (NB + 1) / 2) // 2080 upper-tri blocks = 8 * 260 (bijective swizzle)
#define NSTG 8                   // 8 K-chunks of 64 (K=512)

typedef short s16x8 __attribute__((ext_vector_type(8)));
typedef float f32x4 __attribute__((ext_vector_type(4)));

static __device__ __forceinline__ ushort f2bf(float x) {
    __hip_bfloat16 h = __float2bfloat16(x);
    union { __hip_bfloat16 h; ushort u; } c; c.h = h; return c.u;
}
static __device__ __forceinline__ float bf2f(ushort u) {
    union { __hip_bfloat16 h; ushort u; } c; c.u = u; return __bfloat162float(c.h);
}

// ---------------- kernel 1: normalize + bf16 + target hi/lo pack + wsum parts ----------------
// fpack[n][512] bf16.  tpA/tpB[n][32] bf16 K=32 agree pack:
//   tpA k: [hi(6) | lo(6) | hi(6) | 0...]   tpB k: [hi(6) | hi(6) | lo(6) | 0...]
// one 16x16x32 MFMA = hi.hi + lo.hi + hi.lo  (exact to ~1e-6).
__global__ __launch_bounds__(256) void k_prep(const float* __restrict__ feat,
                                              const float* __restrict__ tgt,
                                              const float* __restrict__ w,
                                              ushort* __restrict__ fpack,
                                              ushort* __restrict__ tpA,
                                              ushort* __restrict__ tpB,
                                              float* __restrict__ partial,
                                              float* __restrict__ wpart) {
    const int wave = threadIdx.x >> 6, lane = threadIdx.x & 63;
    const int row = blockIdx.x * 4 + wave;
    const float* fr = feat + (size_t)row * DIM;
    float4 v0 = *(const float4*)(fr + lane * 4);
    float4 v1 = *(const float4*)(fr + 256 + lane * 4);
    float ss = v0.x*v0.x + v0.y*v0.y + v0.z*v0.z + v0.w*v0.w
             + v1.x*v1.x + v1.y*v1.y + v1.z*v1.z + v1.w*v1.w;
#pragma unroll
    for (int m = 1; m < 64; m <<= 1) ss += __shfl_xor(ss, m);
    const float inv = 1.f / fmaxf(sqrtf(ss), 1e-12f);

    float vals[8] = {v0.x, v0.y, v0.z, v0.w, v1.x, v1.y, v1.z, v1.w};
    ushort hi[8];
#pragma unroll
    for (int i = 0; i < 8; ++i) hi[i] = f2bf(vals[i] * inv);
    ushort* dst = fpack + (size_t)row * 512;
    *(ushort4*)(dst + lane * 4)       = make_ushort4(hi[0], hi[1], hi[2], hi[3]);
    *(ushort4*)(dst + 256 + lane * 4) = make_ushort4(hi[4], hi[5], hi[6], hi[7]);

    // target K=32 pack: lane == k slot
    if (lane < 32) {
        float ta = 0.f, tb = 0.f;
        if (lane < 18) {
            int c = (lane < 6) ? lane : (lane < 12 ? lane - 6 : lane - 12);
            float x = tgt[(size_t)row * NCLS + c];
            ushort h = f2bf(x);
            float hf = bf2f(h);
            float l = x - hf;
            if (lane < 6)       { ta = hf; tb = hf; }
            else if (lane < 12) { ta = l;  tb = hf; }
            else                { ta = hf; tb = l;  }
        }
        tpA[(size_t)row * 32 + lane] = f2bf(ta);
        tpB[(size_t)row * 32 + lane] = f2bf(tb);
    }

    __shared__ float red[4];
    if (lane == 0) {
        partial[row] = 0.f;
        red[wave] = w[row];
    }
    __syncthreads();
    if (threadIdx.x == 0)
        wpart[blockIdx.x] = red[0] + red[1] + red[2] + red[3];
}

// ---------------- staging via global_load_lds (16B), linear LDS dest [G21] ----------------
// 128 rows x 64 bf16 (src stride 512): 1024 chunks of 16B, 256 threads x 4.
__device__ __forceinline__ void stage_f(const ushort* __restrict__ src,
                                        ushort* lds, int tid) {
#pragma unroll
    for (int i = 0; i < 4; ++i) {
        int q = i * 256 + tid;
        int r = q >> 3, c = q & 7;
        __builtin_amdgcn_global_load_lds(
            (const __attribute__((address_space(1))) void*)(src + (size_t)r * 512 + c * 8),
            (__attribute__((address_space(3))) void*)(lds + q * 8),
            16, 0, 0);
    }
}
// 128 rows x 32 bf16 (src stride 32): 512 chunks of 16B, 256 threads x 2.
__device__ __forceinline__ void stage_t(const ushort* __restrict__ src,
                                        ushort* lds, int tid) {
#pragma unroll
    for (int i = 0; i < 2; ++i) {
        int q = i * 256 + tid;
        int r = q >> 2, c = q & 3;
        __builtin_amdgcn_global_load_lds(
            (const __attribute__((address_space(1))) void*)(src + (size_t)r * 32 + c * 8),
            (__attribute__((address_space(3))) void*)(lds + q * 8),
            16, 0, 0);
    }
}

// ---------------- kernel 2: fused upper-tri GEMM + softplus reduction (r3 verbatim) ----------------
// Single-buffer: stage -> sync -> 32 MFMA -> sync, 8 stages (BK=64), then
// K=32 agree stage staged into the same sA/sB. 128x128 tile, 4 waves (2x2).
__global__ __launch_bounds__(256, 3) void k_gemm(
    const ushort* __restrict__ fpack, const ushort* __restrict__ tpA,
    const ushort* __restrict__ tpB, const float* __restrict__ tp,
    const float* __restrict__ bp, float* __restrict__ partial) {

    // bijective XCD swizzle (T1): NTRI = 8*260
    const int orig = blockIdx.x;
    const int b = (orig & 7) * (NTRI / 8) + (orig >> 3);
    // linear index -> upper-tri (bi, bj)
    int bi = 0, rem = b;
    while (rem >= NB - bi) { rem -= NB - bi; ++bi; }
    const int bj = bi + rem;

    __shared__ ushort sA[BM * BK];   // 16 KB
    __shared__ ushort sB[BM * BK];   // 16 KB

    const int tid = threadIdx.x;
    const int lane = tid & 63;
    const int wave = tid >> 6;
    const int wr = wave >> 1, wc = wave & 1;   // 2x2 waves, 64x64 each

    const float tt = *tp, bb = *bp;

    f32x4 accS[4][4], accT[4][4];
#pragma unroll
    for (int i = 0; i < 4; ++i)
#pragma unroll
        for (int j = 0; j < 4; ++j) {
            accS[i][j] = (f32x4){0.f, 0.f, 0.f, 0.f};
            accT[i][j] = (f32x4){0.f, 0.f, 0.f, 0.f};
        }

    const ushort* baseA = fpack + (size_t)(bi * BM) * 512;
    const ushort* baseB = fpack + (size_t)(bj * BM) * 512;

    for (int s = 0; s < NSTG; ++s) {
        stage_f(baseA + s * 64, &sA[0], tid);
        stage_f(baseB + s * 64, &sB[0], tid);
        __syncthreads();
#pragma unroll
        for (int kk = 0; kk < 2; ++kk) {
            s16x8 af[4], bg[4];
            const int kb = kk * 32 + (lane >> 4) * 8;
            const int rr = lane & 15;
#pragma unroll
            for (int i = 0; i < 4; ++i)
                af[i] = *(const s16x8*)(&sA[(wr * 64 + i * 16 + rr) * BK + kb]);
#pragma unroll
            for (int j = 0; j < 4; ++j)
                bg[j] = *(const s16x8*)(&sB[(wc * 64 + j * 16 + rr) * BK + kb]);
#pragma unroll
            for (int i = 0; i < 4; ++i)
#pragma unroll
                for (int j = 0; j < 4; ++j)
                    accS[i][j] = __builtin_amdgcn_mfma_f32_16x16x32_bf16(
                        af[i], bg[j], accS[i][j], 0, 0, 0);
        }
        __syncthreads();
    }

    // ---- agree stage: K=32 target pack ----
    stage_t(tpA + (size_t)(bi * BM) * 32, &sA[0], tid);
    stage_t(tpB + (size_t)(bj * BM) * 32, &sB[0], tid);
    __syncthreads();
    {
        s16x8 af[4], bg[4];
        const int kb = (lane >> 4) * 8;
        const int rr = lane & 15;
#pragma unroll
        for (int i = 0; i < 4; ++i)
            af[i] = *(const s16x8*)(&sA[(wr * 64 + i * 16 + rr) * 32 + kb]);
#pragma unroll
        for (int j = 0; j < 4; ++j)
            bg[j] = *(const s16x8*)(&sB[(wc * 64 + j * 16 + rr) * 32 + kb]);
#pragma unroll
        for (int i = 0; i < 4; ++i)
#pragma unroll
            for (int j = 0; j < 4; ++j)
                accT[i][j] = __builtin_amdgcn_mfma_f32_16x16x32_bf16(
                    af[i], bg[j], accT[i][j], 0, 0, 0);
    }

    // ---- epilogue: agree + softplus + row/col partial sums ----
    // C/D layout (m89): col = lane&15, row = (lane>>4)*4 + r
    float rowsum[4][4];
    float colsum[4];
#pragma unroll
    for (int i = 0; i < 4; ++i)
#pragma unroll
        for (int r = 0; r < 4; ++r) rowsum[i][r] = 0.f;
#pragma unroll
    for (int j = 0; j < 4; ++j) colsum[j] = 0.f;

#pragma unroll
    for (int i = 0; i < 4; ++i)
#pragma unroll
        for (int j = 0; j < 4; ++j)
#pragma unroll
            for (int r = 0; r < 4; ++r) {
                const float agree = fmaf(2.f, accT[i][j][r], -1.f);
                const float e = agree * fmaf(tt, accS[i][j][r], bb);
                // softplus(e), stable: max(e,0) + log(1+exp(-|e|))
                const float sp = fmaxf(e, 0.f) + __logf(1.f + __expf(-fabsf(e)));
                rowsum[i][r] += sp;
                colsum[j] += sp;
            }

    // row sums: reduce across the 16 col-lanes (bits 0..3)
#pragma unroll
    for (int i = 0; i < 4; ++i)
#pragma unroll
        for (int r = 0; r < 4; ++r) {
            float v = rowsum[i][r];
            v += __shfl_xor(v, 1); v += __shfl_xor(v, 2);
            v += __shfl_xor(v, 4); v += __shfl_xor(v, 8);
            if ((lane & 15) == 0)
                atomicAdd(&partial[bi * BM + wr * 64 + i * 16 + (lane >> 4) * 4 + r], v);
        }
    // col sums (transpose contribution), off-diagonal blocks only
    if (bi != bj) {
#pragma unroll
        for (int j = 0; j < 4; ++j) {
            float v = colsum[j];
            v += __shfl_xor(v, 16); v += __shfl_xor(v, 32);
            if (lane < 16)
                atomicAdd(&partial[bj * BM + wc * 64 + j * 16 + lane], v);
        }
    }
}

// ---------------- kernel 3: wsum reduce + final scale ----------------
// loss[n] = (1/N)*rowsum[n] * w[n] / (wsum/N) = rowsum[n] * w[n] / wsum
__global__ __launch_bounds__(256) void k_final(const float* __restrict__ partial,
                                               const float* __restrict__ w,
                                               const float* __restrict__ wpart,
                                               float* __restrict__ out) {
    __shared__ float red[4];
    float s = 0.f;
    for (int i = threadIdx.x; i < NROW / 4; i += 256) s += wpart[i];
#pragma unroll
    for (int m = 1; m < 64; m <<= 1) s += __shfl_xor(s, m);
    if ((threadIdx.x & 63) == 0) red[threadIdx.x >> 6] = s;
    __syncthreads();
    const float wsum = red[0] + red[1] + red[2] + red[3];
    int i = blockIdx.x * 256 + threadIdx.x;
    out[i] = partial[i] * w[i] / wsum;
}

extern "C" void kernel_launch(void* const* d_in, const int* in_sizes, int n_in,
                              void* d_out, int out_size, void* d_ws, size_t ws_size,
                              hipStream_t stream) {
    // inputs: 0=logits(unused), 1=targets, 2=features, 3=weights, 4=t, 5=b
    const float* targets  = (const float*)d_in[1];
    const float* features = (const float*)d_in[2];
    const float* weights  = (const float*)d_in[3];
    const float* tp       = (const float*)d_in[4];
    const float* bp       = (const float*)d_in[5];
    float* out = (float*)d_out;

    // workspace layout (~9.1 MB)
    char* p = (char*)d_ws;
    ushort* fpack   = (ushort*)p; p += (size_t)NROW * 512 * sizeof(ushort); // 8 MB
    ushort* tpA     = (ushort*)p; p += (size_t)NROW * 32 * sizeof(ushort);  // 0.5 MB
    ushort* tpB     = (ushort*)p; p += (size_t)NROW * 32 * sizeof(ushort);  // 0.5 MB
    float*  partial = (float*)p;  p += (size_t)NROW * sizeof(float);        // 32 KB
    float*  wpart   = (float*)p;  p += (size_t)(NROW / 4) * sizeof(float);  // 8 KB

    k_prep<<<NROW / 4, 256, 0, stream>>>(features, targets, weights, fpack, tpA, tpB,
                                         partial, wpart);
    k_gemm<<<NTRI, 256, 0, stream>>>(fpack, tpA, tpB, tp, bp, partial);
    k_final<<<NROW / 256, 256, 0, stream>>>(partial, weights, wpart, out);
}